// Round 18
// baseline (44.353 us; speedup 1.0000x reference)
//
#include <hip/hip_runtime.h>

typedef unsigned short ushort_t;
typedef __bf16 bf16x8 __attribute__((ext_vector_type(8)));
typedef float f32x4 __attribute__((ext_vector_type(4)));

#define AS1 __attribute__((address_space(1)))
#define AS3 __attribute__((address_space(3)))

__device__ __forceinline__ ushort_t f2bf(float f) {
    unsigned u = __builtin_bit_cast(unsigned, f);
    u = (u + 0x7fffu + ((u >> 16) & 1u)) >> 16;
    return (ushort_t)u;
}

__device__ __forceinline__ void async16(void* lds, const void* g) {
    __builtin_amdgcn_global_load_lds((const AS1 unsigned int*)g,
                                     (AS3 unsigned int*)lds, 16, 0, 0);
}

__device__ __forceinline__ void softmax2(const float* __restrict__ sig, float& s0, float& s1) {
    float a = sig[0], b = sig[1];
    float m = fmaxf(a, b);
    float e0 = __expf(a - m), e1 = __expf(b - m);
    float inv = 1.0f / (e0 + e1);
    s0 = e0 * inv; s1 = e1 * inv;
}

// toeplitz value: W_toep[k][o]
__device__ __forceinline__ float toep_val(const float* __restrict__ Wseed, int k, int o) {
    return (k >= o) ? Wseed[(size_t)(k - o) << 10] : Wseed[o - k];
}

// ---------------- merged prep (R4/R17-verified) ----------------
// blocks [0, 4096):    x fp32 [8192][1024] -> xb bf16, 8 elems/thread (coalesced)
// blocks [4096, 4352): 256 blocks, each a 64x64 (k,o) tile of W:
//   read Wseed rows coalesced, transpose via LDS, write Wt[o][k] bf16 coalesced.
__global__ __launch_bounds__(256) void prep_kernel(const float* __restrict__ x,
                                                   const float* __restrict__ Wseed,
                                                   const float* __restrict__ Wsig,
                                                   ushort_t* __restrict__ xb,
                                                   ushort_t* __restrict__ Wt) {
    int b = blockIdx.x;
    if (b < 4096) {
        int i = b * 256 + threadIdx.x;          // 1M threads, 8 elems each
        const float4* xp = (const float4*)x + (size_t)i * 2;
        float4 a = xp[0], c = xp[1];
        uint4 r;
        r.x = (unsigned)f2bf(a.x) | ((unsigned)f2bf(a.y) << 16);
        r.y = (unsigned)f2bf(a.z) | ((unsigned)f2bf(a.w) << 16);
        r.z = (unsigned)f2bf(c.x) | ((unsigned)f2bf(c.y) << 16);
        r.w = (unsigned)f2bf(c.z) | ((unsigned)f2bf(c.w) << 16);
        ((uint4*)xb)[i] = r;
        return;
    }
    __shared__ float T[64][65];
    int bb = b - 4096;                          // 0..255
    int k0 = (bb >> 4) * 64;
    int o0 = (bb & 15) * 64;
    int t = threadIdx.x;
    #pragma unroll
    for (int i = 0; i < 4; ++i) {
        int lin = t + i * 256;
        int kr = lin >> 4;
        int c4 = lin & 15;
        float4 v = *(const float4*)&Wseed[(size_t)(k0 + kr) * 1024 + o0 + c4 * 4];
        T[kr][c4 * 4 + 0] = v.x;
        T[kr][c4 * 4 + 1] = v.y;
        T[kr][c4 * 4 + 2] = v.z;
        T[kr][c4 * 4 + 3] = v.w;
    }
    __syncthreads();
    float s0, s1; softmax2(Wsig, s0, s1);
    #pragma unroll
    for (int i = 0; i < 2; ++i) {
        int lin = t + i * 256;
        int oo = lin >> 3;
        int kq = (lin & 7) * 8;
        unsigned r[4];
        #pragma unroll
        for (int q = 0; q < 4; ++q) {
            float v0 = s0 * T[kq + 2 * q + 0][oo] + s1 * toep_val(Wseed, k0 + kq + 2 * q + 0, o0 + oo);
            float v1 = s0 * T[kq + 2 * q + 1][oo] + s1 * toep_val(Wseed, k0 + kq + 2 * q + 1, o0 + oo);
            r[q] = (unsigned)f2bf(v0) | ((unsigned)f2bf(v1) << 16);
        }
        *(uint4*)&Wt[(size_t)(o0 + oo) * 1024 + k0 + kq] = make_uint4(r[0], r[1], r[2], r[3]);
    }
}

// ---------------- main GEMM: 128x128, BK=128, 8 drains total ----------------
// Fitted model (R15/R17): per-step cost = C*(BK/32) + O with O≈0.28us fixed.
// BK=128 -> 8 steps: GEMM ≈ 24+8*0.28 ≈ 26us if O survives 1-block/CU.
// 512 threads = 8 waves (4Mx2N, per-wave 32x64, 32 MFMA/step). LDS 128 KB dbuf
// (A 32KB + B 32KB per buf) -> 1 resident block/CU; grid 512 = 2 passes.
// 256B rows -> XOR swizzle chunk ^= row&15 on BOTH operands (banks 2-way, free);
// staging: 16 thr/row, call q = +32 rows, dest linear ushort q*4096 + t*8.
#define BM 128
#define BN 128
#define BK 128
#define NKT 8    // 1024 / 128

__global__ __launch_bounds__(512, 1) void gemm_kernel(const ushort_t* __restrict__ Xb,
                                                      const ushort_t* __restrict__ Wt,
                                                      const float* __restrict__ bseed,
                                                      const float* __restrict__ bsig,
                                                      const float* __restrict__ asig,
                                                      float* __restrict__ out) {
    // dbuf x (A 16384 + B 16384 ushorts) = 131072 B
    __shared__ ushort_t lds[65536];
    ushort_t* At0 = lds;             // [128 rows][128 k] bf16
    ushort_t* Bt0 = lds + 16384;
    ushort_t* At1 = lds + 32768;
    ushort_t* Bt1 = lds + 49152;

    const int t = threadIdx.x;        // 0..511
    const int wv = t >> 6;            // 0..7
    const int lane = t & 63;

    // XCD-aware swizzle (512 blocks, bijective)
    const int orig = blockIdx.x;
    const int g = orig & 7;
    const int within = orig >> 3;           // 0..63
    const int rb = g * 8 + (within >> 3);   // row-block 0..63
    const int cb = within & 7;              // col-block 0..7
    const int brow = rb * BM;
    const int bcol = cb * BN;

    // staging map: 16 threads per 256B row; rows 0..31 per call; chunk ^= row&15
    const int rs = t >> 4;                        // 0..31
    const int cs = (t & 15) ^ (rs & 15);          // inverse-swizzled 16B chunk
    const ushort_t* gA = Xb + (size_t)(brow + rs) * 1024 + 8 * cs;
    const ushort_t* gB = Wt + (size_t)(bcol + rs) * 1024 + 8 * cs;

    f32x4 acc[2][4];
    #pragma unroll
    for (int i = 0; i < 2; ++i)
        #pragma unroll
        for (int j = 0; j < 4; ++j) acc[i][j] = (f32x4){0.f, 0.f, 0.f, 0.f};

    // wave decomposition: 4 M-groups x 2 N-groups; wave = 32 rows x 64 cols
    const int wr = (wv >> 1) * 32;     // 0,32,64,96
    const int wcn = (wv & 1) * 64;     // 0,64
    const int fr = lane & 15;
    const int kq = lane >> 4;          // 0..3: 8-elem group within 32-k chunk

    // epilogue scalars precomputed + pinned
    float bs0, bs1, as0, as1;
    softmax2(bsig, bs0, bs1);
    softmax2(asig, as0, as1);
    float bias[4];
    #pragma unroll
    for (int ni = 0; ni < 4; ++ni)
        bias[ni] = bs0 * bseed[bcol + wcn + ni * 16 + fr];
    asm volatile("" :: "v"(bias[0]), "v"(bias[1]), "v"(bias[2]), "v"(bias[3]),
                       "v"(as0), "v"(as1));
    asm volatile("" ::: "memory");

// 4 calls x 8KB per operand; call q covers rows q*32..q*32+31
// dest linear: ushort off = q*4096 + t*8 (= row*128 + chunk*8, pre-swizzled src)
#define STAGE1(buf, gptr, ko)                                       \
    do {                                                            \
        async16((buf) + wv * 512,         (gptr) + (ko));           \
        async16((buf) + 4096 + wv * 512,  (gptr) + 32768 + (ko));   \
        async16((buf) + 8192 + wv * 512,  (gptr) + 65536 + (ko));   \
        async16((buf) + 12288 + wv * 512, (gptr) + 98304 + (ko));   \
    } while (0)

#define STAGE(Abuf, Bbuf, ko) do { STAGE1(Abuf, gA, ko); STAGE1(Bbuf, gB, ko); } while (0)

// fragment read: ushort off = row*128 + 8*((h*4+kq) ^ (row&15)), h = 0..3
#define COMPUTE(Abuf, Bbuf)                                                        \
    do {                                                                           \
        _Pragma("unroll")                                                          \
        for (int h = 0; h < 4; ++h) {                                              \
            bf16x8 af[2], bf[4];                                                   \
            _Pragma("unroll")                                                      \
            for (int mi = 0; mi < 2; ++mi) {                                       \
                int row_ = wr + mi * 16 + fr;                                      \
                int ch_ = (h * 4 + kq) ^ (row_ & 15);                              \
                af[mi] = *(const bf16x8*)&(Abuf)[row_ * 128 + ch_ * 8];            \
            }                                                                      \
            _Pragma("unroll")                                                      \
            for (int ni = 0; ni < 4; ++ni) {                                       \
                int row_ = wcn + ni * 16 + fr;                                     \
                int ch_ = (h * 4 + kq) ^ (row_ & 15);                              \
                bf[ni] = *(const bf16x8*)&(Bbuf)[row_ * 128 + ch_ * 8];            \
            }                                                                      \
            _Pragma("unroll")                                                      \
            for (int mi = 0; mi < 2; ++mi)                                         \
                _Pragma("unroll")                                                  \
                for (int ni = 0; ni < 4; ++ni)                                     \
                    acc[mi][ni] = __builtin_amdgcn_mfma_f32_16x16x32_bf16(         \
                        af[mi], bf[ni], acc[mi][ni], 0, 0, 0);                     \
        }                                                                          \
    } while (0)

#define SYNC() do { asm volatile("s_waitcnt vmcnt(0) lgkmcnt(0)" ::: "memory");    \
                    __builtin_amdgcn_s_barrier(); } while (0)

    // prologue: K-tile 0 into buf0
    STAGE(At0, Bt0, 0);
    SYNC();
    // main: 3 double-iterations (tiles 0..5)
    for (int it = 0; it < 3; ++it) {
        STAGE(At1, Bt1, (2 * it + 1) * BK);
        COMPUTE(At0, Bt0);
        SYNC();
        STAGE(At0, Bt0, (2 * it + 2) * BK);
        COMPUTE(At1, Bt1);
        SYNC();
    }
    // tail: tiles 6, 7
    STAGE(At1, Bt1, 7 * BK);
    COMPUTE(At0, Bt0);
    SYNC();
    COMPUTE(At1, Bt1);

    // epilogue: bias + activation mixture
    #pragma unroll
    for (int ni = 0; ni < 4; ++ni) {
        int col = bcol + wcn + ni * 16 + fr;
        #pragma unroll
        for (int mi = 0; mi < 2; ++mi) {
            int row = brow + wr + mi * 16 + (lane >> 4) * 4;
            #pragma unroll
            for (int r = 0; r < 4; ++r) {
                float v = acc[mi][ni][r] + bias[ni];
                out[(size_t)(row + r) * 1024 + col] = as0 * v + as1 * fmaxf(v, 0.f);
            }
        }
    }
#undef STAGE1
#undef STAGE
#undef COMPUTE
#undef SYNC
}

// ---------------- fallback (only if workspace too small): naive fp32 ----------------
__global__ __launch_bounds__(256) void naive_kernel(const float* __restrict__ x,
                                                    const float* __restrict__ Wseed,
                                                    const float* __restrict__ bseed,
                                                    const float* __restrict__ Wsig,
                                                    const float* __restrict__ bsig,
                                                    const float* __restrict__ asig,
                                                    float* __restrict__ out) {
    int idx = blockIdx.x * 256 + threadIdx.x;
    int b = idx >> 10, o = idx & 1023;
    float ws0, ws1, bs0, bs1, as0, as1;
    softmax2(Wsig, ws0, ws1);
    softmax2(bsig, bs0, bs1);
    softmax2(asig, as0, as1);
    float s = 0.f;
    const float* xr = x + (size_t)b * 1024;
    for (int k = 0; k < 1024; ++k) {
        float wc = ws0 * Wseed[((size_t)k << 10) + o] + ws1 * toep_val(Wseed, k, o);
        s += xr[k] * wc;
    }
    float v = s + bs0 * bseed[o];
    out[idx] = as0 * v + as1 * fmaxf(v, 0.f);
}

extern "C" void kernel_launch(void* const* d_in, const int* in_sizes, int n_in,
                              void* d_out, int out_size, void* d_ws, size_t ws_size,
                              hipStream_t stream) {
    const float* x     = (const float*)d_in[0];
    const float* Wseed = (const float*)d_in[1];
    const float* bseed = (const float*)d_in[2];
    const float* Wsig  = (const float*)d_in[3];
    const float* bsig  = (const float*)d_in[4];
    const float* Asig  = (const float*)d_in[5];
    float* out = (float*)d_out;

    const size_t need = (2u << 20) + (16u << 20) + 1024;
    if (ws_size < need) {
        naive_kernel<<<dim3(8192 * 1024 / 256), dim3(256), 0, stream>>>(
            x, Wseed, bseed, Wsig, bsig, Asig, out);
        return;
    }

    ushort_t* Wt = (ushort_t*)d_ws;                         // 2 MB: W_core^T bf16 [1024][1024]
    ushort_t* Xb = (ushort_t*)((char*)d_ws + (2u << 20));   // 16 MB: x bf16 [8192][1024]

    prep_kernel<<<dim3(4096 + 256), dim3(256), 0, stream>>>(x, Wseed, Wsig, Xb, Wt);
    gemm_kernel<<<dim3(512), dim3(512), 0, stream>>>(Xb, Wt, bseed, bsig, Asig, out);
}

// Round 19
// 37.028 us; speedup vs baseline: 1.1978x; 1.1978x over previous
//
#include <hip/hip_runtime.h>

typedef unsigned short ushort_t;
typedef __bf16 bf16x8 __attribute__((ext_vector_type(8)));
typedef float f32x4 __attribute__((ext_vector_type(4)));

#define AS1 __attribute__((address_space(1)))
#define AS3 __attribute__((address_space(3)))

__device__ __forceinline__ ushort_t f2bf(float f) {
    unsigned u = __builtin_bit_cast(unsigned, f);
    u = (u + 0x7fffu + ((u >> 16) & 1u)) >> 16;
    return (ushort_t)u;
}

__device__ __forceinline__ void async16(void* lds, const void* g) {
    __builtin_amdgcn_global_load_lds((const AS1 unsigned int*)g,
                                     (AS3 unsigned int*)lds, 16, 0, 0);
}

__device__ __forceinline__ void softmax2(const float* __restrict__ sig, float& s0, float& s1) {
    float a = sig[0], b = sig[1];
    float m = fmaxf(a, b);
    float e0 = __expf(a - m), e1 = __expf(b - m);
    float inv = 1.0f / (e0 + e1);
    s0 = e0 * inv; s1 = e1 * inv;
}

// toeplitz value: W_toep[k][o]
__device__ __forceinline__ float toep_val(const float* __restrict__ Wseed, int k, int o) {
    return (k >= o) ? Wseed[(size_t)(k - o) << 10] : Wseed[o - k];
}

// ---------------- prep: W_core^T bf16 only (~2us; x consumed fp32 by GEMM) --------
__global__ __launch_bounds__(256) void prep_w_kernel(const float* __restrict__ Wseed,
                                                     const float* __restrict__ Wsig,
                                                     ushort_t* __restrict__ Wt) {
    __shared__ float T[64][65];
    int bb = blockIdx.x;                        // 0..255
    int k0 = (bb >> 4) * 64;
    int o0 = (bb & 15) * 64;
    int t = threadIdx.x;
    #pragma unroll
    for (int i = 0; i < 4; ++i) {
        int lin = t + i * 256;
        int kr = lin >> 4;
        int c4 = lin & 15;
        float4 v = *(const float4*)&Wseed[(size_t)(k0 + kr) * 1024 + o0 + c4 * 4];
        T[kr][c4 * 4 + 0] = v.x;
        T[kr][c4 * 4 + 1] = v.y;
        T[kr][c4 * 4 + 2] = v.z;
        T[kr][c4 * 4 + 3] = v.w;
    }
    __syncthreads();
    float s0, s1; softmax2(Wsig, s0, s1);
    #pragma unroll
    for (int i = 0; i < 2; ++i) {
        int lin = t + i * 256;
        int oo = lin >> 3;
        int kq = (lin & 7) * 8;
        unsigned r[4];
        #pragma unroll
        for (int q = 0; q < 4; ++q) {
            float v0 = s0 * T[kq + 2 * q + 0][oo] + s1 * toep_val(Wseed, k0 + kq + 2 * q + 0, o0 + oo);
            float v1 = s0 * T[kq + 2 * q + 1][oo] + s1 * toep_val(Wseed, k0 + kq + 2 * q + 1, o0 + oo);
            r[q] = (unsigned)f2bf(v0) | ((unsigned)f2bf(v1) << 16);
        }
        *(uint4*)&Wt[(size_t)(o0 + oo) * 1024 + k0 + kq] = make_uint4(r[0], r[1], r[2], r[3]);
    }
}

// ---------------- main GEMM: R17 geometry + fused x->bf16 A-staging ----------------
// 128x128, BK=64, 256 threads = 4 waves (2x2, wave 64x64, 32 MFMA/step), grid 512
// = 2 blocks/CU. LDS 64 KB: A bf16 dbuf 32KB + B bf16 dbuf 32KB (R17-proven).
// A path: fp32 x -> regs with 2-STEP LEAD (double-buffered reg sets aE/aO) ->
// cvt+ds_write one step before use. B: async16 from Wt, 1-step lead (R17-proven).
// vmcnt ledger (issue order per step t: STAGEB(t+1)x4, LOADA(t+2)x8):
//   WRITEA(t+1) implicit reg-dep wait = vmcnt(12) [retires A(t+1), issued t-1]
//   end-of-step vmcnt(8) retires B(t+1); A(t+2)'s 8 loads stay in flight.
// Race ledger: WRITEA(t+1)->abuf[(t+1)&1] has no concurrent reader (compute reads
// abuf[t&1]); prior content consumed at t-1, barrier passed. lgkmcnt(0)+barrier
// publishes ds_writes before t+1's reads. Epilogue scalars consumed+pinned
// pre-prologue so the ledger stays exact.
#define BM 128
#define BN 128
#define BK 64
#define NKT 16   // 1024 / 64

__global__ __launch_bounds__(256, 2) void gemm_kernel(const float* __restrict__ Xf,
                                                      const ushort_t* __restrict__ Wt,
                                                      const float* __restrict__ bseed,
                                                      const float* __restrict__ bsig,
                                                      const float* __restrict__ asig,
                                                      float* __restrict__ out) {
    __shared__ ushort_t lds[32768];   // 64 KB
    ushort_t* const A0buf = lds;              // [128][64] bf16 (8192 ushorts)
    ushort_t* const A1buf = lds + 8192;
    ushort_t* const B0buf = lds + 16384;
    ushort_t* const B1buf = lds + 24576;

    const int t = threadIdx.x;        // 0..255
    const int wv = t >> 6;            // 0..3
    const int lane = t & 63;

    // XCD-aware swizzle (512 blocks, bijective)
    const int orig = blockIdx.x;
    const int g = orig & 7;
    const int within = orig >> 3;           // 0..63
    const int rb = g * 8 + (within >> 3);   // row-block 0..63
    const int cb = within & 7;              // col-block 0..7
    const int brow = rb * BM;
    const int bcol = cb * BN;

    // ---- B staging map (R17-verified): 8 thr/128B-row, src chunk pre-XOR'd ----
    const int rs = t >> 3;                        // 0..31
    const int cs = (t & 7) ^ (rs & 7);            // inverse-swizzled 16B chunk
    const ushort_t* gB = Wt + (size_t)(bcol + rs) * 1024 + 8 * cs;

    // ---- A load map: thread covers 8 floats of row (t>>3)+q*32, k (t&7)*8 ----
    const float* gX = Xf + (size_t)(brow + (t >> 3)) * 1024 + (t & 7) * 8;
    // A ds_write offset (swizzle applied at WRITE address; row&7 == (t>>3)&7 all q)
    const int wbase = (t >> 3) * 64 + (((t & 7) ^ ((t >> 3) & 7)) << 3);

    // fragment geometry: wave = 64x64 (2Mx2N waves)
    const int wr = (wv >> 1) * 64;     // 0,64
    const int wcn = (wv & 1) * 64;     // 0,64
    const int fr = lane & 15;
    const int kq = lane >> 4;          // 0..3

    f32x4 acc[4][4];
    #pragma unroll
    for (int i = 0; i < 4; ++i)
        #pragma unroll
        for (int j = 0; j < 4; ++j) acc[i][j] = (f32x4){0.f, 0.f, 0.f, 0.f};

    // epilogue scalars precomputed + pinned (ledger integrity)
    float bs0, bs1, as0, as1;
    softmax2(bsig, bs0, bs1);
    softmax2(asig, as0, as1);
    float bias[4];
    #pragma unroll
    for (int ni = 0; ni < 4; ++ni)
        bias[ni] = bs0 * bseed[bcol + wcn + ni * 16 + fr];
    asm volatile("" :: "v"(bias[0]), "v"(bias[1]), "v"(bias[2]), "v"(bias[3]),
                       "v"(as0), "v"(as1));
    asm volatile("" ::: "memory");

    // A staging register sets (even/odd tiles), statically named (rule #20)
    f32x4 aE0, aE1, aE2, aE3, aE4, aE5, aE6, aE7;
    f32x4 aO0, aO1, aO2, aO3, aO4, aO5, aO6, aO7;

#define LOADA(P, ko)                                                   \
    do {                                                               \
        P##0 = *(const f32x4*)(gX + (ko));                             \
        P##1 = *(const f32x4*)(gX + (ko) + 4);                         \
        P##2 = *(const f32x4*)(gX + 32768 + (ko));                     \
        P##3 = *(const f32x4*)(gX + 32768 + (ko) + 4);                 \
        P##4 = *(const f32x4*)(gX + 65536 + (ko));                     \
        P##5 = *(const f32x4*)(gX + 65536 + (ko) + 4);                 \
        P##6 = *(const f32x4*)(gX + 98304 + (ko));                     \
        P##7 = *(const f32x4*)(gX + 98304 + (ko) + 4);                 \
    } while (0)

#define CVW(Abuf, off, rlo, rhi)                                       \
    do {                                                               \
        bf16x8 v_;                                                     \
        _Pragma("unroll")                                              \
        for (int j_ = 0; j_ < 4; ++j_) {                               \
            v_[j_]     = (__bf16)rlo[j_];                              \
            v_[4 + j_] = (__bf16)rhi[j_];                              \
        }                                                              \
        *(bf16x8*)&(Abuf)[(off)] = v_;                                 \
    } while (0)

#define WRITEA(Abuf, P)                                                \
    do {                                                               \
        CVW(Abuf, wbase,        P##0, P##1);                           \
        CVW(Abuf, wbase + 2048, P##2, P##3);                           \
        CVW(Abuf, wbase + 4096, P##4, P##5);                           \
        CVW(Abuf, wbase + 6144, P##6, P##7);                           \
    } while (0)

#define STAGEB(buf, ko)                                                \
    do {                                                               \
        async16((buf) + wv * 512,        gB + (ko));                   \
        async16((buf) + 2048 + wv * 512, gB + 32768 + (ko));           \
        async16((buf) + 4096 + wv * 512, gB + 65536 + (ko));           \
        async16((buf) + 6144 + wv * 512, gB + 98304 + (ko));           \
    } while (0)

// R17-verified fragment reads: chunk = (kq [+4]) ^ (row&7)
#define COMPUTE(Abuf, Bbuf)                                                        \
    do {                                                                           \
        bf16x8 af[4][2], bf[4][2];                                                 \
        _Pragma("unroll")                                                          \
        for (int mi = 0; mi < 4; ++mi) {                                           \
            int row_ = wr + mi * 16 + fr;                                          \
            af[mi][0] = *(const bf16x8*)&(Abuf)[row_ * 64 + (((kq)     ^ (row_ & 7)) << 3)]; \
            af[mi][1] = *(const bf16x8*)&(Abuf)[row_ * 64 + (((kq + 4) ^ (row_ & 7)) << 3)]; \
        }                                                                          \
        _Pragma("unroll")                                                          \
        for (int ni = 0; ni < 4; ++ni) {                                           \
            int row_ = wcn + ni * 16 + fr;                                         \
            bf[ni][0] = *(const bf16x8*)&(Bbuf)[row_ * 64 + (((kq)     ^ (row_ & 7)) << 3)]; \
            bf[ni][1] = *(const bf16x8*)&(Bbuf)[row_ * 64 + (((kq + 4) ^ (row_ & 7)) << 3)]; \
        }                                                                          \
        _Pragma("unroll")                                                          \
        for (int mi = 0; mi < 4; ++mi)                                             \
            _Pragma("unroll")                                                      \
            for (int ni = 0; ni < 4; ++ni) {                                       \
                acc[mi][ni] = __builtin_amdgcn_mfma_f32_16x16x32_bf16(             \
                    af[mi][0], bf[ni][0], acc[mi][ni], 0, 0, 0);                   \
                acc[mi][ni] = __builtin_amdgcn_mfma_f32_16x16x32_bf16(             \
                    af[mi][1], bf[ni][1], acc[mi][ni], 0, 0, 0);                   \
            }                                                                      \
    } while (0)

#define ENDSYNC8() do { asm volatile("" ::: "memory");                               \
                        asm volatile("s_waitcnt vmcnt(8)" ::: "memory");             \
                        asm volatile("s_waitcnt lgkmcnt(0)" ::: "memory");           \
                        __builtin_amdgcn_s_barrier(); } while (0)
#define ENDSYNC0() do { asm volatile("" ::: "memory");                               \
                        asm volatile("s_waitcnt vmcnt(0) lgkmcnt(0)" ::: "memory");  \
                        __builtin_amdgcn_s_barrier(); } while (0)

    // ---- prologue: A(0)->aE, B(0)->B0, A(1)->aO; write A(0); retire B(0) ----
    LOADA(aE, 0);                 // 8 vm
    STAGEB(B0buf, 0);             // 4 vm
    LOADA(aO, 64);                // 8 vm
    WRITEA(A0buf, aE);            // implicit vmcnt(12): retires A(0)
    ENDSYNC8();                   // retires B(0); A(1)'s 8 stay in flight

    // ---- main: 7 double-steps (t = 0..13) ----
    for (int i = 0; i < 7; ++i) {
        const int T = 2 * i;
        // even step T: compute A0buf/B0; stage B(T+1); load A(T+2) into aE
        STAGEB(B1buf, (size_t)(T + 1) * BK);
        LOADA(aE, (size_t)(T + 2) * BK);
        WRITEA(A1buf, aO);        // implicit vmcnt(12): retires A(T+1)
        COMPUTE(A0buf, B0buf);
        ENDSYNC8();               // retires B(T+1); A(T+2) in flight
        // odd step T+1: compute A1buf/B1; stage B(T+2); load A(T+3) into aO
        STAGEB(B0buf, (size_t)(T + 2) * BK);
        LOADA(aO, (size_t)(T + 3) * BK);
        WRITEA(A0buf, aE);        // implicit vmcnt(12): retires A(T+2)
        COMPUTE(A1buf, B1buf);
        ENDSYNC8();               // retires B(T+2); A(T+3) in flight
    }
    // ---- tail: t = 14, 15 ----
    STAGEB(B1buf, 15 * BK);       // B(15)
    WRITEA(A1buf, aO);            // implicit wait: retires A(15)
    COMPUTE(A0buf, B0buf);        // tile 14
    ENDSYNC0();                   // drain all (B(15) included)
    COMPUTE(A1buf, B1buf);        // tile 15

    // epilogue: bias + activation mixture
    #pragma unroll
    for (int ni = 0; ni < 4; ++ni) {
        int col = bcol + wcn + ni * 16 + fr;
        #pragma unroll
        for (int mi = 0; mi < 4; ++mi) {
            int row = brow + wr + mi * 16 + (lane >> 4) * 4;
            #pragma unroll
            for (int r = 0; r < 4; ++r) {
                float v = acc[mi][ni][r] + bias[ni];
                out[(size_t)(row + r) * 1024 + col] = as0 * v + as1 * fmaxf(v, 0.f);
            }
        }
    }
#undef LOADA
#undef CVW
#undef WRITEA
#undef STAGEB
#undef COMPUTE
#undef ENDSYNC8
#undef ENDSYNC0
}

// ---------------- fallback (only if workspace too small): naive fp32 ----------------
__global__ __launch_bounds__(256) void naive_kernel(const float* __restrict__ x,
                                                    const float* __restrict__ Wseed,
                                                    const float* __restrict__ bseed,
                                                    const float* __restrict__ Wsig,
                                                    const float* __restrict__ bsig,
                                                    const float* __restrict__ asig,
                                                    float* __restrict__ out) {
    int idx = blockIdx.x * 256 + threadIdx.x;
    int b = idx >> 10, o = idx & 1023;
    float ws0, ws1, bs0, bs1, as0, as1;
    softmax2(Wsig, ws0, ws1);
    softmax2(bsig, bs0, bs1);
    softmax2(asig, as0, as1);
    float s = 0.f;
    const float* xr = x + (size_t)b * 1024;
    for (int k = 0; k < 1024; ++k) {
        float wc = ws0 * Wseed[((size_t)k << 10) + o] + ws1 * toep_val(Wseed, k, o);
        s += xr[k] * wc;
    }
    float v = s + bs0 * bseed[o];
    out[idx] = as0 * v + as1 * fmaxf(v, 0.f);
}

extern "C" void kernel_launch(void* const* d_in, const int* in_sizes, int n_in,
                              void* d_out, int out_size, void* d_ws, size_t ws_size,
                              hipStream_t stream) {
    const float* x     = (const float*)d_in[0];
    const float* Wseed = (const float*)d_in[1];
    const float* bseed = (const float*)d_in[2];
    const float* Wsig  = (const float*)d_in[3];
    const float* bsig  = (const float*)d_in[4];
    const float* Asig  = (const float*)d_in[5];
    float* out = (float*)d_out;

    const size_t need = (2u << 20) + 1024;
    if (ws_size < need) {
        naive_kernel<<<dim3(8192 * 1024 / 256), dim3(256), 0, stream>>>(
            x, Wseed, bseed, Wsig, bsig, Asig, out);
        return;
    }

    ushort_t* Wt = (ushort_t*)d_ws;   // 2 MB: W_core^T bf16 [1024][1024]

    prep_w_kernel<<<dim3(256), dim3(256), 0, stream>>>(Wseed, Wsig, Wt);
    gemm_kernel<<<dim3(512), dim3(256), 0, stream>>>(x, Wt, bseed, bsig, Asig, out);
}

// Round 20
// 35.610 us; speedup vs baseline: 1.2455x; 1.0398x over previous
//
#include <hip/hip_runtime.h>

typedef unsigned short ushort_t;
typedef __bf16 bf16x8 __attribute__((ext_vector_type(8)));
typedef float f32x4 __attribute__((ext_vector_type(4)));

#define AS1 __attribute__((address_space(1)))
#define AS3 __attribute__((address_space(3)))

__device__ __forceinline__ ushort_t f2bf(float f) {
    unsigned u = __builtin_bit_cast(unsigned, f);
    u = (u + 0x7fffu + ((u >> 16) & 1u)) >> 16;
    return (ushort_t)u;
}

__device__ __forceinline__ void async16(void* lds, const void* g) {
    __builtin_amdgcn_global_load_lds((const AS1 unsigned int*)g,
                                     (AS3 unsigned int*)lds, 16, 0, 0);
}

__device__ __forceinline__ void softmax2(const float* __restrict__ sig, float& s0, float& s1) {
    float a = sig[0], b = sig[1];
    float m = fmaxf(a, b);
    float e0 = __expf(a - m), e1 = __expf(b - m);
    float inv = 1.0f / (e0 + e1);
    s0 = e0 * inv; s1 = e1 * inv;
}

// toeplitz value: W_toep[k][o]
__device__ __forceinline__ float toep_val(const float* __restrict__ Wseed, int k, int o) {
    return (k >= o) ? Wseed[(size_t)(k - o) << 10] : Wseed[o - k];
}

// ---------------- prep: W_core^T bf16 only (~2us) ----------------
__global__ __launch_bounds__(256) void prep_w_kernel(const float* __restrict__ Wseed,
                                                     const float* __restrict__ Wsig,
                                                     ushort_t* __restrict__ Wt) {
    __shared__ float T[64][65];
    int bb = blockIdx.x;                        // 0..255
    int k0 = (bb >> 4) * 64;
    int o0 = (bb & 15) * 64;
    int t = threadIdx.x;
    #pragma unroll
    for (int i = 0; i < 4; ++i) {
        int lin = t + i * 256;
        int kr = lin >> 4;
        int c4 = lin & 15;
        float4 v = *(const float4*)&Wseed[(size_t)(k0 + kr) * 1024 + o0 + c4 * 4];
        T[kr][c4 * 4 + 0] = v.x;
        T[kr][c4 * 4 + 1] = v.y;
        T[kr][c4 * 4 + 2] = v.z;
        T[kr][c4 * 4 + 3] = v.w;
    }
    __syncthreads();
    float s0, s1; softmax2(Wsig, s0, s1);
    #pragma unroll
    for (int i = 0; i < 2; ++i) {
        int lin = t + i * 256;
        int oo = lin >> 3;
        int kq = (lin & 7) * 8;
        unsigned r[4];
        #pragma unroll
        for (int q = 0; q < 4; ++q) {
            float v0 = s0 * T[kq + 2 * q + 0][oo] + s1 * toep_val(Wseed, k0 + kq + 2 * q + 0, o0 + oo);
            float v1 = s0 * T[kq + 2 * q + 1][oo] + s1 * toep_val(Wseed, k0 + kq + 2 * q + 1, o0 + oo);
            r[q] = (unsigned)f2bf(v0) | ((unsigned)f2bf(v1) << 16);
        }
        *(uint4*)&Wt[(size_t)(o0 + oo) * 1024 + k0 + kq] = make_uint4(r[0], r[1], r[2], r[3]);
    }
}

// ---------------- main GEMM: R19 fused-A + 8 waves (the last untested cell) -------
// 128x128, BK=64, 512 threads = 8 waves (4Mx2N, wave 32x64, 16 MFMA/step),
// grid 512 = 2 blocks/CU -> 16 waves/CU (2x R19's TLP to hide the staging chain).
// A: fp32 x -> regs, 2-step lead (aE/aO), cvt+ds_write one step before use.
// B: async16 from Wt, 1-step lead. XOR swizzle chunk ^= row&7 both operands.
// vmcnt ledger (per step issue: STAGEB(t+1)x2, LOADA(t+2)x4):
//   WRITEA implicit reg-dep wait = vmcnt(6) [retires A(t+1)]
//   ENDSYNC vmcnt(4) retires B(t+1); A(t+2)'s 4 loads stay in flight.
#define BM 128
#define BN 128
#define BK 64
#define NKT 16   // 1024 / 64

__global__ __launch_bounds__(512, 2) void gemm_kernel(const float* __restrict__ Xf,
                                                      const ushort_t* __restrict__ Wt,
                                                      const float* __restrict__ bseed,
                                                      const float* __restrict__ bsig,
                                                      const float* __restrict__ asig,
                                                      float* __restrict__ out) {
    __shared__ ushort_t lds[32768];   // 64 KB
    ushort_t* const A0buf = lds;              // [128][64] bf16 (8192 ushorts)
    ushort_t* const A1buf = lds + 8192;
    ushort_t* const B0buf = lds + 16384;
    ushort_t* const B1buf = lds + 24576;

    const int t = threadIdx.x;        // 0..511
    const int wv = t >> 6;            // 0..7
    const int lane = t & 63;

    // XCD-aware swizzle (512 blocks, bijective)
    const int orig = blockIdx.x;
    const int g = orig & 7;
    const int within = orig >> 3;           // 0..63
    const int rb = g * 8 + (within >> 3);   // row-block 0..63
    const int cb = within & 7;              // col-block 0..7
    const int brow = rb * BM;
    const int bcol = cb * BN;

    // shared staging map: 8 thr per 128B row; rows (t>>3) and +64; chunk pre-XOR'd
    const int rs = t >> 3;                        // 0..63
    const int cs = (t & 7) ^ (rs & 7);            // inverse-swizzled 16B chunk
    const ushort_t* gB = Wt + (size_t)(bcol + rs) * 1024 + 8 * cs;
    const float*    gX = Xf + (size_t)(brow + rs) * 1024 + (t & 7) * 8;
    // A ds_write offset (swizzle at write address; row&7 == rs&7 for both halves)
    const int wbase = rs * 64 + (cs << 3);

    // fragment geometry: 4 M-groups x 2 N-groups; wave = 32 rows x 64 cols
    const int wr = (wv >> 1) * 32;     // 0,32,64,96
    const int wcn = (wv & 1) * 64;     // 0,64
    const int fr = lane & 15;
    const int kq = lane >> 4;          // 0..3

    f32x4 acc[2][4];
    #pragma unroll
    for (int i = 0; i < 2; ++i)
        #pragma unroll
        for (int j = 0; j < 4; ++j) acc[i][j] = (f32x4){0.f, 0.f, 0.f, 0.f};

    // epilogue scalars precomputed + pinned (ledger integrity)
    float bs0, bs1, as0, as1;
    softmax2(bsig, bs0, bs1);
    softmax2(asig, as0, as1);
    float bias[4];
    #pragma unroll
    for (int ni = 0; ni < 4; ++ni)
        bias[ni] = bs0 * bseed[bcol + wcn + ni * 16 + fr];
    asm volatile("" :: "v"(bias[0]), "v"(bias[1]), "v"(bias[2]), "v"(bias[3]),
                       "v"(as0), "v"(as1));
    asm volatile("" ::: "memory");

    // A staging register sets (even/odd tiles), statically named (rule #20)
    f32x4 aE0, aE1, aE2, aE3, aO0, aO1, aO2, aO3;

#define LOADA(P, ko)                                                   \
    do {                                                               \
        P##0 = *(const f32x4*)(gX + (ko));                             \
        P##1 = *(const f32x4*)(gX + (ko) + 4);                         \
        P##2 = *(const f32x4*)(gX + 65536 + (ko));                     \
        P##3 = *(const f32x4*)(gX + 65536 + (ko) + 4);                 \
    } while (0)

#define CVW(Abuf, off, rlo, rhi)                                       \
    do {                                                               \
        bf16x8 v_;                                                     \
        _Pragma("unroll")                                              \
        for (int j_ = 0; j_ < 4; ++j_) {                               \
            v_[j_]     = (__bf16)rlo[j_];                              \
            v_[4 + j_] = (__bf16)rhi[j_];                              \
        }                                                              \
        *(bf16x8*)&(Abuf)[(off)] = v_;                                 \
    } while (0)

#define WRITEA(Abuf, P)                                                \
    do {                                                               \
        CVW(Abuf, wbase,        P##0, P##1);                           \
        CVW(Abuf, wbase + 4096, P##2, P##3);                           \
    } while (0)

#define STAGEB(buf, ko)                                                \
    do {                                                               \
        async16((buf) + wv * 512,        gB + (ko));                   \
        async16((buf) + 4096 + wv * 512, gB + 65536 + (ko));           \
    } while (0)

// fragment reads: chunk = (kq [+4]) ^ (row&7)
#define COMPUTE(Abuf, Bbuf)                                                        \
    do {                                                                           \
        bf16x8 af[2][2], bf[4][2];                                                 \
        _Pragma("unroll")                                                          \
        for (int mi = 0; mi < 2; ++mi) {                                           \
            int row_ = wr + mi * 16 + fr;                                          \
            af[mi][0] = *(const bf16x8*)&(Abuf)[row_ * 64 + (((kq)     ^ (row_ & 7)) << 3)]; \
            af[mi][1] = *(const bf16x8*)&(Abuf)[row_ * 64 + (((kq + 4) ^ (row_ & 7)) << 3)]; \
        }                                                                          \
        _Pragma("unroll")                                                          \
        for (int ni = 0; ni < 4; ++ni) {                                           \
            int row_ = wcn + ni * 16 + fr;                                         \
            bf[ni][0] = *(const bf16x8*)&(Bbuf)[row_ * 64 + (((kq)     ^ (row_ & 7)) << 3)]; \
            bf[ni][1] = *(const bf16x8*)&(Bbuf)[row_ * 64 + (((kq + 4) ^ (row_ & 7)) << 3)]; \
        }                                                                          \
        _Pragma("unroll")                                                          \
        for (int mi = 0; mi < 2; ++mi)                                             \
            _Pragma("unroll")                                                      \
            for (int ni = 0; ni < 4; ++ni) {                                       \
                acc[mi][ni] = __builtin_amdgcn_mfma_f32_16x16x32_bf16(             \
                    af[mi][0], bf[ni][0], acc[mi][ni], 0, 0, 0);                   \
                acc[mi][ni] = __builtin_amdgcn_mfma_f32_16x16x32_bf16(             \
                    af[mi][1], bf[ni][1], acc[mi][ni], 0, 0, 0);                   \
            }                                                                      \
    } while (0)

#define ENDSYNC4() do { asm volatile("" ::: "memory");                               \
                        asm volatile("s_waitcnt vmcnt(4)" ::: "memory");             \
                        asm volatile("s_waitcnt lgkmcnt(0)" ::: "memory");           \
                        __builtin_amdgcn_s_barrier(); } while (0)
#define ENDSYNC0() do { asm volatile("" ::: "memory");                               \
                        asm volatile("s_waitcnt vmcnt(0) lgkmcnt(0)" ::: "memory");  \
                        __builtin_amdgcn_s_barrier(); } while (0)

    // ---- prologue: A(0)->aE, B(0)->B0, A(1)->aO; write A(0); retire B(0) ----
    LOADA(aE, 0);                 // 4 vm
    STAGEB(B0buf, 0);             // 2 vm
    LOADA(aO, 64);                // 4 vm
    WRITEA(A0buf, aE);            // implicit vmcnt(6): retires A(0)
    ENDSYNC4();                   // retires B(0); A(1)'s 4 stay in flight

    // ---- main: 7 double-steps (t = 0..13) ----
    for (int i = 0; i < 7; ++i) {
        const int T = 2 * i;
        STAGEB(B1buf, (size_t)(T + 1) * BK);
        LOADA(aE, (size_t)(T + 2) * BK);
        WRITEA(A1buf, aO);        // implicit vmcnt(6): retires A(T+1)
        COMPUTE(A0buf, B0buf);
        ENDSYNC4();               // retires B(T+1); A(T+2) in flight
        STAGEB(B0buf, (size_t)(T + 2) * BK);
        LOADA(aO, (size_t)(T + 3) * BK);
        WRITEA(A0buf, aE);        // implicit vmcnt(6): retires A(T+2)
        COMPUTE(A1buf, B1buf);
        ENDSYNC4();               // retires B(T+2); A(T+3) in flight
    }
    // ---- tail: t = 14, 15 ----
    STAGEB(B1buf, 15 * BK);       // B(15)
    WRITEA(A1buf, aO);            // implicit vmcnt(2): retires A(15)
    COMPUTE(A0buf, B0buf);        // tile 14
    ENDSYNC0();                   // drain all (B(15) included)
    COMPUTE(A1buf, B1buf);        // tile 15

    // epilogue: bias + activation mixture
    #pragma unroll
    for (int ni = 0; ni < 4; ++ni) {
        int col = bcol + wcn + ni * 16 + fr;
        #pragma unroll
        for (int mi = 0; mi < 2; ++mi) {
            int row = brow + wr + mi * 16 + (lane >> 4) * 4;
            #pragma unroll
            for (int r = 0; r < 4; ++r) {
                float v = acc[mi][ni][r] + bias[ni];
                out[(size_t)(row + r) * 1024 + col] = as0 * v + as1 * fmaxf(v, 0.f);
            }
        }
    }
#undef LOADA
#undef CVW
#undef WRITEA
#undef STAGEB
#undef COMPUTE
#undef ENDSYNC4
#undef ENDSYNC0
}

// ---------------- fallback (only if workspace too small): naive fp32 ----------------
__global__ __launch_bounds__(256) void naive_kernel(const float* __restrict__ x,
                                                    const float* __restrict__ Wseed,
                                                    const float* __restrict__ bseed,
                                                    const float* __restrict__ Wsig,
                                                    const float* __restrict__ bsig,
                                                    const float* __restrict__ asig,
                                                    float* __restrict__ out) {
    int idx = blockIdx.x * 256 + threadIdx.x;
    int b = idx >> 10, o = idx & 1023;
    float ws0, ws1, bs0, bs1, as0, as1;
    softmax2(Wsig, ws0, ws1);
    softmax2(bsig, bs0, bs1);
    softmax2(asig, as0, as1);
    float s = 0.f;
    const float* xr = x + (size_t)b * 1024;
    for (int k = 0; k < 1024; ++k) {
        float wc = ws0 * Wseed[((size_t)k << 10) + o] + ws1 * toep_val(Wseed, k, o);
        s += xr[k] * wc;
    }
    float v = s + bs0 * bseed[o];
    out[idx] = as0 * v + as1 * fmaxf(v, 0.f);
}

extern "C" void kernel_launch(void* const* d_in, const int* in_sizes, int n_in,
                              void* d_out, int out_size, void* d_ws, size_t ws_size,
                              hipStream_t stream) {
    const float* x     = (const float*)d_in[0];
    const float* Wseed = (const float*)d_in[1];
    const float* bseed = (const float*)d_in[2];
    const float* Wsig  = (const float*)d_in[3];
    const float* bsig  = (const float*)d_in[4];
    const float* Asig  = (const float*)d_in[5];
    float* out = (float*)d_out;

    const size_t need = (2u << 20) + 1024;
    if (ws_size < need) {
        naive_kernel<<<dim3(8192 * 1024 / 256), dim3(256), 0, stream>>>(
            x, Wseed, bseed, Wsig, bsig, Asig, out);
        return;
    }

    ushort_t* Wt = (ushort_t*)d_ws;   // 2 MB: W_core^T bf16 [1024][1024]

    prep_w_kernel<<<dim3(256), dim3(256), 0, stream>>>(Wseed, Wsig, Wt);
    gemm_kernel<<<dim3(512), dim3(512), 0, stream>>>(x, Wt, bseed, bsig, Asig, out);
}

// Round 22
// 35.587 us; speedup vs baseline: 1.2463x; 1.0006x over previous
//
#include <hip/hip_runtime.h>

typedef unsigned short ushort_t;
typedef __bf16 bf16x8 __attribute__((ext_vector_type(8)));
typedef float f32x4 __attribute__((ext_vector_type(4)));

#define AS1 __attribute__((address_space(1)))
#define AS3 __attribute__((address_space(3)))

__device__ __forceinline__ ushort_t f2bf(float f) {
    unsigned u = __builtin_bit_cast(unsigned, f);
    u = (u + 0x7fffu + ((u >> 16) & 1u)) >> 16;
    return (ushort_t)u;
}

__device__ __forceinline__ void async16(void* lds, const void* g) {
    __builtin_amdgcn_global_load_lds((const AS1 unsigned int*)g,
                                     (AS3 unsigned int*)lds, 16, 0, 0);
}

__device__ __forceinline__ void softmax2(const float* __restrict__ sig, float& s0, float& s1) {
    float a = sig[0], b = sig[1];
    float m = fmaxf(a, b);
    float e0 = __expf(a - m), e1 = __expf(b - m);
    float inv = 1.0f / (e0 + e1);
    s0 = e0 * inv; s1 = e1 * inv;
}

// toeplitz value: W_toep[k][o]
__device__ __forceinline__ float toep_val(const float* __restrict__ Wseed, int k, int o) {
    return (k >= o) ? Wseed[(size_t)(k - o) << 10] : Wseed[o - k];
}

// ---------------- prep: W_core^T bf16 only (~2us) ----------------
__global__ __launch_bounds__(256) void prep_w_kernel(const float* __restrict__ Wseed,
                                                     const float* __restrict__ Wsig,
                                                     ushort_t* __restrict__ Wt) {
    __shared__ float T[64][65];
    int bb = blockIdx.x;                        // 0..255
    int k0 = (bb >> 4) * 64;
    int o0 = (bb & 15) * 64;
    int t = threadIdx.x;
    #pragma unroll
    for (int i = 0; i < 4; ++i) {
        int lin = t + i * 256;
        int kr = lin >> 4;
        int c4 = lin & 15;
        float4 v = *(const float4*)&Wseed[(size_t)(k0 + kr) * 1024 + o0 + c4 * 4];
        T[kr][c4 * 4 + 0] = v.x;
        T[kr][c4 * 4 + 1] = v.y;
        T[kr][c4 * 4 + 2] = v.z;
        T[kr][c4 * 4 + 3] = v.w;
    }
    __syncthreads();
    float s0, s1; softmax2(Wsig, s0, s1);
    #pragma unroll
    for (int i = 0; i < 2; ++i) {
        int lin = t + i * 256;
        int oo = lin >> 3;
        int kq = (lin & 7) * 8;
        unsigned r[4];
        #pragma unroll
        for (int q = 0; q < 4; ++q) {
            float v0 = s0 * T[kq + 2 * q + 0][oo] + s1 * toep_val(Wseed, k0 + kq + 2 * q + 0, o0 + oo);
            float v1 = s0 * T[kq + 2 * q + 1][oo] + s1 * toep_val(Wseed, k0 + kq + 2 * q + 1, o0 + oo);
            r[q] = (unsigned)f2bf(v0) | ((unsigned)f2bf(v1) << 16);
        }
        *(uint4*)&Wt[(size_t)(o0 + oo) * 1024 + k0 + kq] = make_uint4(r[0], r[1], r[2], r[3]);
    }
}

// ---------------- main GEMM: R20 final form (best measured: 35.6us total) ---------
// 128x128, BK=64, 512 threads = 8 waves (4Mx2N, wave 32x64, 16 MFMA/step),
// grid 512 = 2 blocks/CU -> 16 waves/CU.
// A: fp32 x -> regs, 2-step lead (aE/aO), cvt+ds_write one step before use.
// B: async16 from Wt, 1-step lead. XOR swizzle chunk ^= row&7 both operands.
// vmcnt ledger (per step issue: STAGEB(t+1)x2, LOADA(t+2)x4):
//   WRITEA implicit reg-dep wait = vmcnt(6) [retires A(t+1)]
//   ENDSYNC vmcnt(4) retires B(t+1); A(t+2)'s 4 loads stay in flight.
// NOTE (R21 lesson): this ledger assumes STAGEB issues before LOADA; R20's
// compiled schedule preserves it (verified by passing). Do not re-derive
// without pinning issue order.
#define BM 128
#define BN 128
#define BK 64
#define NKT 16   // 1024 / 64

__global__ __launch_bounds__(512, 2) void gemm_kernel(const float* __restrict__ Xf,
                                                      const ushort_t* __restrict__ Wt,
                                                      const float* __restrict__ bseed,
                                                      const float* __restrict__ bsig,
                                                      const float* __restrict__ asig,
                                                      float* __restrict__ out) {
    __shared__ ushort_t lds[32768];   // 64 KB
    ushort_t* const A0buf = lds;              // [128][64] bf16 (8192 ushorts)
    ushort_t* const A1buf = lds + 8192;
    ushort_t* const B0buf = lds + 16384;
    ushort_t* const B1buf = lds + 24576;

    const int t = threadIdx.x;        // 0..511
    const int wv = t >> 6;            // 0..7
    const int lane = t & 63;

    // XCD-aware swizzle (512 blocks, bijective)
    const int orig = blockIdx.x;
    const int g = orig & 7;
    const int within = orig >> 3;           // 0..63
    const int rb = g * 8 + (within >> 3);   // row-block 0..63
    const int cb = within & 7;              // col-block 0..7
    const int brow = rb * BM;
    const int bcol = cb * BN;

    // shared staging map: 8 thr per 128B row; rows (t>>3) and +64; chunk pre-XOR'd
    const int rs = t >> 3;                        // 0..63
    const int cs = (t & 7) ^ (rs & 7);            // inverse-swizzled 16B chunk
    const ushort_t* gB = Wt + (size_t)(bcol + rs) * 1024 + 8 * cs;
    const float*    gX = Xf + (size_t)(brow + rs) * 1024 + (t & 7) * 8;
    // A ds_write offset (swizzle at write address; row&7 == rs&7 for both halves)
    const int wbase = rs * 64 + (cs << 3);

    // fragment geometry: 4 M-groups x 2 N-groups; wave = 32 rows x 64 cols
    const int wr = (wv >> 1) * 32;     // 0,32,64,96
    const int wcn = (wv & 1) * 64;     // 0,64
    const int fr = lane & 15;
    const int kq = lane >> 4;          // 0..3

    f32x4 acc[2][4];
    #pragma unroll
    for (int i = 0; i < 2; ++i)
        #pragma unroll
        for (int j = 0; j < 4; ++j) acc[i][j] = (f32x4){0.f, 0.f, 0.f, 0.f};

    // epilogue scalars precomputed + pinned (ledger integrity)
    float bs0, bs1, as0, as1;
    softmax2(bsig, bs0, bs1);
    softmax2(asig, as0, as1);
    float bias[4];
    #pragma unroll
    for (int ni = 0; ni < 4; ++ni)
        bias[ni] = bs0 * bseed[bcol + wcn + ni * 16 + fr];
    asm volatile("" :: "v"(bias[0]), "v"(bias[1]), "v"(bias[2]), "v"(bias[3]),
                       "v"(as0), "v"(as1));
    asm volatile("" ::: "memory");

    // A staging register sets (even/odd tiles), statically named (rule #20)
    f32x4 aE0, aE1, aE2, aE3, aO0, aO1, aO2, aO3;

#define LOADA(P, ko)                                                   \
    do {                                                               \
        P##0 = *(const f32x4*)(gX + (ko));                             \
        P##1 = *(const f32x4*)(gX + (ko) + 4);                         \
        P##2 = *(const f32x4*)(gX + 65536 + (ko));                     \
        P##3 = *(const f32x4*)(gX + 65536 + (ko) + 4);                 \
    } while (0)

#define CVW(Abuf, off, rlo, rhi)                                       \
    do {                                                               \
        bf16x8 v_;                                                     \
        _Pragma("unroll")                                              \
        for (int j_ = 0; j_ < 4; ++j_) {                               \
            v_[j_]     = (__bf16)rlo[j_];                              \
            v_[4 + j_] = (__bf16)rhi[j_];                              \
        }                                                              \
        *(bf16x8*)&(Abuf)[(off)] = v_;                                 \
    } while (0)

#define WRITEA(Abuf, P)                                                \
    do {                                                               \
        CVW(Abuf, wbase,        P##0, P##1);                           \
        CVW(Abuf, wbase + 4096, P##2, P##3);                           \
    } while (0)

#define STAGEB(buf, ko)                                                \
    do {                                                               \
        async16((buf) + wv * 512,        gB + (ko));                   \
        async16((buf) + 4096 + wv * 512, gB + 65536 + (ko));           \
    } while (0)

// fragment reads: chunk = (kq [+4]) ^ (row&7)
#define COMPUTE(Abuf, Bbuf)                                                        \
    do {                                                                           \
        bf16x8 af[2][2], bf[4][2];                                                 \
        _Pragma("unroll")                                                          \
        for (int mi = 0; mi < 2; ++mi) {                                           \
            int row_ = wr + mi * 16 + fr;                                          \
            af[mi][0] = *(const bf16x8*)&(Abuf)[row_ * 64 + (((kq)     ^ (row_ & 7)) << 3)]; \
            af[mi][1] = *(const bf16x8*)&(Abuf)[row_ * 64 + (((kq + 4) ^ (row_ & 7)) << 3)]; \
        }                                                                          \
        _Pragma("unroll")                                                          \
        for (int ni = 0; ni < 4; ++ni) {                                           \
            int row_ = wcn + ni * 16 + fr;                                         \
            bf[ni][0] = *(const bf16x8*)&(Bbuf)[row_ * 64 + (((kq)     ^ (row_ & 7)) << 3)]; \
            bf[ni][1] = *(const bf16x8*)&(Bbuf)[row_ * 64 + (((kq + 4) ^ (row_ & 7)) << 3)]; \
        }                                                                          \
        _Pragma("unroll")                                                          \
        for (int mi = 0; mi < 2; ++mi)                                             \
            _Pragma("unroll")                                                      \
            for (int ni = 0; ni < 4; ++ni) {                                       \
                acc[mi][ni] = __builtin_amdgcn_mfma_f32_16x16x32_bf16(             \
                    af[mi][0], bf[ni][0], acc[mi][ni], 0, 0, 0);                   \
                acc[mi][ni] = __builtin_amdgcn_mfma_f32_16x16x32_bf16(             \
                    af[mi][1], bf[ni][1], acc[mi][ni], 0, 0, 0);                   \
            }                                                                      \
    } while (0)

#define ENDSYNC4() do { asm volatile("" ::: "memory");                               \
                        asm volatile("s_waitcnt vmcnt(4)" ::: "memory");             \
                        asm volatile("s_waitcnt lgkmcnt(0)" ::: "memory");           \
                        __builtin_amdgcn_s_barrier(); } while (0)
#define ENDSYNC0() do { asm volatile("" ::: "memory");                               \
                        asm volatile("s_waitcnt vmcnt(0) lgkmcnt(0)" ::: "memory");  \
                        __builtin_amdgcn_s_barrier(); } while (0)

    // ---- prologue: A(0)->aE, B(0)->B0, A(1)->aO; write A(0); retire B(0) ----
    LOADA(aE, 0);                 // 4 vm
    STAGEB(B0buf, 0);             // 2 vm
    LOADA(aO, 64);                // 4 vm
    WRITEA(A0buf, aE);            // implicit vmcnt(6): retires A(0)
    ENDSYNC4();                   // retires B(0); A(1)'s 4 stay in flight

    // ---- main: 7 double-steps (t = 0..13) ----
    for (int i = 0; i < 7; ++i) {
        const int T = 2 * i;
        STAGEB(B1buf, (size_t)(T + 1) * BK);
        LOADA(aE, (size_t)(T + 2) * BK);
        WRITEA(A1buf, aO);        // implicit vmcnt(6): retires A(T+1)
        COMPUTE(A0buf, B0buf);
        ENDSYNC4();               // retires B(T+1); A(T+2) in flight
        STAGEB(B0buf, (size_t)(T + 2) * BK);
        LOADA(aO, (size_t)(T + 3) * BK);
        WRITEA(A0buf, aE);        // implicit vmcnt(6): retires A(T+2)
        COMPUTE(A1buf, B1buf);
        ENDSYNC4();               // retires B(T+2); A(T+3) in flight
    }
    // ---- tail: t = 14, 15 ----
    STAGEB(B1buf, 15 * BK);       // B(15)
    WRITEA(A1buf, aO);            // implicit vmcnt(2): retires A(15)
    COMPUTE(A0buf, B0buf);        // tile 14
    ENDSYNC0();                   // drain all (B(15) included)
    COMPUTE(A1buf, B1buf);        // tile 15

    // epilogue: bias + activation mixture
    #pragma unroll
    for (int ni = 0; ni < 4; ++ni) {
        int col = bcol + wcn + ni * 16 + fr;
        #pragma unroll
        for (int mi = 0; mi < 2; ++mi) {
            int row = brow + wr + mi * 16 + (lane >> 4) * 4;
            #pragma unroll
            for (int r = 0; r < 4; ++r) {
                float v = acc[mi][ni][r] + bias[ni];
                out[(size_t)(row + r) * 1024 + col] = as0 * v + as1 * fmaxf(v, 0.f);
            }
        }
    }
#undef LOADA
#undef CVW
#undef WRITEA
#undef STAGEB
#undef COMPUTE
#undef ENDSYNC4
#undef ENDSYNC0
}

// ---------------- fallback (only if workspace too small): naive fp32 ----------------
__global__ __launch_bounds__(256) void naive_kernel(const float* __restrict__ x,
                                                    const float* __restrict__ Wseed,
                                                    const float* __restrict__ bseed,
                                                    const float* __restrict__ Wsig,
                                                    const float* __restrict__ bsig,
                                                    const float* __restrict__ asig,
                                                    float* __restrict__ out) {
    int idx = blockIdx.x * 256 + threadIdx.x;
    int b = idx >> 10, o = idx & 1023;
    float ws0, ws1, bs0, bs1, as0, as1;
    softmax2(Wsig, ws0, ws1);
    softmax2(bsig, bs0, bs1);
    softmax2(asig, as0, as1);
    float s = 0.f;
    const float* xr = x + (size_t)b * 1024;
    for (int k = 0; k < 1024; ++k) {
        float wc = ws0 * Wseed[((size_t)k << 10) + o] + ws1 * toep_val(Wseed, k, o);
        s += xr[k] * wc;
    }
    float v = s + bs0 * bseed[o];
    out[idx] = as0 * v + as1 * fmaxf(v, 0.f);
}

extern "C" void kernel_launch(void* const* d_in, const int* in_sizes, int n_in,
                              void* d_out, int out_size, void* d_ws, size_t ws_size,
                              hipStream_t stream) {
    const float* x     = (const float*)d_in[0];
    const float* Wseed = (const float*)d_in[1];
    const float* bseed = (const float*)d_in[2];
    const float* Wsig  = (const float*)d_in[3];
    const float* bsig  = (const float*)d_in[4];
    const float* Asig  = (const float*)d_in[5];
    float* out = (float*)d_out;

    const size_t need = (2u << 20) + 1024;
    if (ws_size < need) {
        naive_kernel<<<dim3(8192 * 1024 / 256), dim3(256), 0, stream>>>(
            x, Wseed, bseed, Wsig, bsig, Asig, out);
        return;
    }

    ushort_t* Wt = (ushort_t*)d_ws;   // 2 MB: W_core^T bf16 [1024][1024]

    prep_w_kernel<<<dim3(256), dim3(256), 0, stream>>>(Wseed, Wsig, Wt);
    gemm_kernel<<<dim3(512), dim3(512), 0, stream>>>(x, Wt, bseed, bsig, Asig, out);
}